// Round 2
// baseline (562.540 us; speedup 1.0000x reference)
//
#include <hip/hip_runtime.h>
#include <stdint.h>

// JAX threefry counter mode. 1 = partitionable (modern JAX default, >=0.4.30).
#define THREEFRY_PARTITIONABLE 1

#define DEV_HOST __host__ __device__

namespace {
constexpr int kNS = 10;
constexpr int kNB = 512;     // persistent grid: 8 samples per block

// workspace layout (float offsets)
constexpr int OFF_SUF     = 0;          // S[j][d][h]: 128*64*32 = 262144
constexpr int OFF_U       = 262144;     // u[s][d] handoff for final assembly
constexpr int OFF_SNRM    = 524288;     // 10 per-step ||score||^2 accumulators
constexpr int OFF_BAR     = 524300;     // 12 barriers x 8 counters x 16 stride
constexpr int BAR_UINTS   = 12 * 8 * 16;
constexpr int OFF_LOSSBLK = OFF_BAR + BAR_UINTS;   // [blk]{step_loss, |e-x| sum}
constexpr int ZACC_N      = 12 + BAR_UINTS;        // snrm+pad+bars zeroed
constexpr int WS_FLOATS   = OFF_LOSSBLK + 2 * kNB;
}

// ---------------- threefry2x32-20 (matches jax/_src/prng.py) ----------------
DEV_HOST inline void tf2x32(uint32_t k0, uint32_t k1, uint32_t x0, uint32_t x1,
                            uint32_t& o0, uint32_t& o1) {
  const uint32_t k2 = k0 ^ k1 ^ 0x1BD11BDAu;
#define TF_R(r) { x0 += x1; x1 = (x1 << (r)) | (x1 >> (32 - (r))); x1 ^= x0; }
  x0 += k0; x1 += k1;
  TF_R(13) TF_R(15) TF_R(26) TF_R(6)
  x0 += k1; x1 += k2 + 1u;
  TF_R(17) TF_R(29) TF_R(16) TF_R(24)
  x0 += k2; x1 += k0 + 2u;
  TF_R(13) TF_R(15) TF_R(26) TF_R(6)
  x0 += k0; x1 += k1 + 3u;
  TF_R(17) TF_R(29) TF_R(16) TF_R(24)
  x0 += k1; x1 += k2 + 4u;
  TF_R(13) TF_R(15) TF_R(26) TF_R(6)
  x0 += k2; x1 += k0 + 5u;
#undef TF_R
  o0 = x0; o1 = x1;
}

__device__ inline uint32_t rand_bits(uint32_t key0, uint32_t key1, uint32_t idx) {
#if THREEFRY_PARTITIONABLE
  uint32_t y0, y1;
  tf2x32(key0, key1, 0u, idx, y0, y1);
  return y0 ^ y1;
#else
  const uint32_t half = 262144u / 2;
  uint32_t y0, y1;
  if (idx < half) { tf2x32(key0, key1, idx, half + idx, y0, y1); return y0; }
  tf2x32(key0, key1, idx - half, idx, y0, y1);
  return y1;
#endif
}

// ------------- XLA ErfInv (f32, Giles poly) + jax.random.normal -------------
__device__ inline float erfinv_xla(float x) {
  float w = -log1pf(-x * x);
  float p;
  if (w < 5.0f) {
    w = w - 2.5f;
    p = 2.81022636e-08f;
    p = fmaf(p, w, 3.43273939e-07f);
    p = fmaf(p, w, -3.5233877e-06f);
    p = fmaf(p, w, -4.39150654e-06f);
    p = fmaf(p, w, 0.00021858087f);
    p = fmaf(p, w, -0.00125372503f);
    p = fmaf(p, w, -0.00417768164f);
    p = fmaf(p, w, 0.246640727f);
    p = fmaf(p, w, 1.50140941f);
  } else {
    w = sqrtf(w) - 3.0f;
    p = -0.000200214257f;
    p = fmaf(p, w, 0.000100950558f);
    p = fmaf(p, w, 0.00134934322f);
    p = fmaf(p, w, -0.00367342844f);
    p = fmaf(p, w, 0.00573950773f);
    p = fmaf(p, w, -0.0076224613f);
    p = fmaf(p, w, 0.00943887047f);
    p = fmaf(p, w, 1.00167406f);
    p = fmaf(p, w, 2.83297682f);
  }
  return p * x;
}

__device__ inline float bits_to_normal(uint32_t bits) {
  const float lo = -0.99999994039535522f;  // nextafter(-1,0) in f32
  float f = __uint_as_float((bits >> 9) | 0x3f800000u) - 1.0f;
  float u = fmaxf(lo, f * 2.0f + lo);
  return 1.41421356237309515f * erfinv_xla(u);  // sqrt(2) in f32
}

// ---------------------------------------------------------------------------
// Grid barrier: 8-way-split arrival counters (64B apart), relaxed spin +
// agent fences. All kNB blocks are co-resident (__launch_bounds__(256,2)
// guarantees 2 blocks/CU x 256 CUs = 512 slots; blocks never retire early).
__device__ inline void gridbar(unsigned* b8, unsigned nblk, bool wait) {
  __syncthreads();
  if (threadIdx.x == 0) {
    __threadfence();  // release: flush our stores/atomics device-wide
    __hip_atomic_fetch_add(b8 + (blockIdx.x & 7) * 16, 1u,
                           __ATOMIC_RELEASE, __HIP_MEMORY_SCOPE_AGENT);
    if (wait) {
      for (;;) {
        unsigned tot = 0;
#pragma unroll
        for (int i = 0; i < 8; ++i)
          tot += __hip_atomic_load(b8 + i * 16, __ATOMIC_RELAXED,
                                   __HIP_MEMORY_SCOPE_AGENT);
        if (tot >= nblk) break;
        __builtin_amdgcn_s_sleep(1);
      }
      __threadfence();  // acquire: invalidate stale caches before consuming
    }
  }
  __syncthreads();
}

// ---------------------------------------------------------------------------
// S[j][d][h] = sum_{t>j} W1[(t*64+d)*32 + h]; also zero snrm + barriers.
__global__ __launch_bounds__(256) void k_suffix(const float* __restrict__ W1,
                                                float* __restrict__ S,
                                                float* __restrict__ zacc) {
  const int p = blockIdx.x * 256 + threadIdx.x;  // 2048 threads: (d,h)
  if (p < ZACC_N) zacc[p] = 0.0f;
  if (p >= 2048) return;
  const int d = p >> 5, h = p & 31;
  float acc = 0.0f;
  S[(127 * 64 + d) * 32 + h] = 0.0f;
  for (int j = 126; j >= 0; --j) {
    acc += W1[((j + 1) * 64 + d) * 32 + h];
    S[(j * 64 + d) * 32 + h] = acc;
  }
}

// ---------------------------------------------------------------------------
struct FusedParams {
  const float* S;
  const float* emb;
  const float* W1;
  const float* b1;
  const float* W2;
  const float* b2;
  float* u;
  float* out;
  float* snrm;
  float* lossblk;   // [kNB][2]: {step_loss partial, sum|emb-xt| partial}
  unsigned* bar;
  uint32_t key0[kNS];
  uint32_t key1[kNS];
};

// Persistent-grid fused kernel. u/score live in registers (block owns 8
// samples; thread (sl,c) owns elements (s,c),(s,c+32)). Per step the only
// grid-wide dependency is the scalar snorm -> one gridbar per step (+2).
// Loss: per-thread register accumulation, per-block slot write (plain
// stores through the barrier — no cross-block atomics, no sub-wave shfl).
__global__ __launch_bounds__(256, 2) void k_fused(FusedParams p) {
  __shared__ float u_sh[8][64];
  __shared__ float h_sh[8][32];
  __shared__ float wsum[4];
  __shared__ float wsumB[4];
  const int tid = threadIdx.x;
  const int blk = blockIdx.x;
  const unsigned nb = gridDim.x;
  const int s0 = blk * 8;
  const int sl = tid >> 5, c = tid & 31;
  const int s = s0 + sl;
  const int jw = s & 127;                    // W1 row-block (dynamic part)
  const bool contrib = (jw == (s >> 5));     // sample feeds error accumulator

  // ---- hoist this thread's W1 column into registers (step-invariant) ----
  float w1reg[64];
  {
    const float* w1r = p.W1 + (jw * 64) * 32 + c;
#pragma unroll
    for (int d = 0; d < 64; ++d) w1reg[d] = w1r[d * 32];
  }
  const float w1t  = p.W1[8192 * 32 + c];
  const float b2_0 = p.b2[c], b2_1 = p.b2[c + 32];

  // ---- fused k_base: base[s][h=c], thread-local (same (s,h) layout) ----
  float basev;
  {
    const int jj = s >> 5, bb = s & 31;
    const float* e  = p.emb + (bb * 128 + jj) * 64;
    const float* Sp = p.S + (jj * 64) * 32 + c;
    float acc = p.b1[c];
#pragma unroll 16
    for (int d = 0; d < 64; ++d) acc = fmaf(e[d], Sp[d * 32], acc);
    basev = acc;
  }

  float u0 = 0.0f, u1 = 0.0f;   // u[s][c], u[s][c+32] in registers
  float lacc = 0.0f;            // per-thread step-loss accumulator

  for (int k = 0; k < kNS; ++k) {
    // stage u into LDS for the 64-d dot product
    u_sh[sl][c]      = u0;
    u_sh[sl][c + 32] = u1;
    __syncthreads();
    // hidden pre-activation + relu, thread = (sl, h=c)
    const float tval = (float)k * 0.1f;
    float pre = fmaf(tval, w1t, basev);
#pragma unroll
    for (int d = 0; d < 64; ++d) pre = fmaf(u_sh[sl][d], w1reg[d], pre);
    h_sh[sl][c] = fmaxf(pre, 0.0f);
    __syncthreads();
    // score = relu(h) @ W2 + b2, thread = (sl, cols c and c+32)
    float sc0 = b2_0, sc1 = b2_1;
#pragma unroll
    for (int hh = 0; hh < 32; ++hh) {
      const float hv = h_sh[sl][hh];
      sc0 = fmaf(hv, p.W2[hh * 64 + c], sc0);
      sc1 = fmaf(hv, p.W2[hh * 64 + c + 32], sc1);
    }
    // block-partial ||score||^2 (64-wide reduce, proven construct)
    float sq = fmaf(sc0, sc0, sc1 * sc1);
#pragma unroll
    for (int o = 32; o > 0; o >>= 1) sq += __shfl_down(sq, o);
    if ((tid & 63) == 0) wsum[tid >> 6] = sq;
    // RNG is snorm-independent: compute BEFORE the barrier.
    const uint32_t e0 = (uint32_t)(s * 64 + c);
    const float n0 = bits_to_normal(rand_bits(p.key0[k], p.key1[k], e0));
    const float n1 = bits_to_normal(rand_bits(p.key0[k], p.key1[k], e0 + 32u));
    __syncthreads();
    if (tid == 0) atomicAdd(p.snrm + k, wsum[0] + wsum[1] + wsum[2] + wsum[3]);
    gridbar(p.bar + k * 128, nb, true);
    // update u with completed snorm
    const float snorm = sqrtf(__hip_atomic_load(p.snrm + k, __ATOMIC_RELAXED,
                                                __HIP_MEMORY_SCOPE_AGENT));
    u0 = u0 + (sc0 * 0.05f + snorm * (n0 * 0.31622776601683794f));
    u1 = u1 + (sc1 * 0.05f + snorm * (n1 * 0.31622776601683794f));
    // error[i,b] += mean_d(u^2): accumulate in a register, reduce at end
    if (contrib) lacc = fmaf(u0, u0, fmaf(u1, u1, lacc));
  }

  // ---- hand off u to global for the cross-sample final assembly ----
  p.u[s * 64 + c]      = u0;
  p.u[s * 64 + c + 32] = u1;
  gridbar(p.bar + kNS * 128, nb, true);

  // ---- fused k_final: assemble xt output + sum|emb-xt| (2 elems/thread) ----
  float lsum = 0.0f;
#pragma unroll
  for (int r = 0; r < 2; ++r) {
    const int g = blk * 256 + tid + r * 131072;  // g = (b*128+i)*64+d
    const int d = g & 63, bi = g >> 6, i = bi & 127, b = bi >> 7;
    const int m = i * 32 + b;
    const int bp = m >> 7, t = m & 127;
    const int ss = i * 32 + bp;
    float v = 0.0f;
    if (i < t) v = p.emb[(bp * 128 + i) * 64 + d];
    if ((ss & 127) == t) v += p.u[ss * 64 + d];
    p.out[g] = v;
    lsum += fabsf(p.emb[g] - v);
  }
  // block-reduce both loss partials (64-wide shuffles + LDS, proven)
  float la = lacc * (1.0f / 64.0f);
#pragma unroll
  for (int o = 32; o > 0; o >>= 1) {
    la   += __shfl_down(la, o);
    lsum += __shfl_down(lsum, o);
  }
  if ((tid & 63) == 0) { wsum[tid >> 6] = la; wsumB[tid >> 6] = lsum; }
  __syncthreads();
  if (tid == 0) {
    p.lossblk[2 * blk]     = wsum[0] + wsum[1] + wsum[2] + wsum[3];
    p.lossblk[2 * blk + 1] = wsumB[0] + wsumB[1] + wsumB[2] + wsumB[3];
  }

  // only block 0 needs to wait here; everyone else arrives and exits
  gridbar(p.bar + (kNS + 1) * 128, nb, blk == 0);
  if (blk == 0) {
    float a = 0.0f, m = 0.0f;
    for (int q = tid; q < kNB; q += 256) {
      a += p.lossblk[2 * q];
      m += p.lossblk[2 * q + 1];
    }
#pragma unroll
    for (int o = 32; o > 0; o >>= 1) {
      a += __shfl_down(a, o);
      m += __shfl_down(m, o);
    }
    if ((tid & 63) == 0) { wsum[tid >> 6] = a; wsumB[tid >> 6] = m; }
    __syncthreads();
    if (tid == 0) {
      p.out[262144] = wsum[0] + wsum[1] + wsum[2] + wsum[3];                     // step_loss
      p.out[262145] = (wsumB[0] + wsumB[1] + wsumB[2] + wsumB[3]) * (1.0f / 262144.0f);
    }
  }
}

// ---------------------------------------------------------------------------
static void compute_step_keys(uint32_t keys[kNS][2]) {
#if THREEFRY_PARTITIONABLE
  for (int i = 0; i < kNS; ++i) {
    uint32_t y0, y1;
    tf2x32(0u, 42u, 0u, (uint32_t)i, y0, y1);
    keys[i][0] = y0; keys[i][1] = y1;
  }
#else
  uint32_t a[kNS], b[kNS], outw[2 * kNS];
  for (int i = 0; i < kNS; ++i)
    tf2x32(0u, 42u, (uint32_t)i, (uint32_t)(kNS + i), a[i], b[i]);
  for (int i = 0; i < kNS; ++i) { outw[i] = a[i]; outw[kNS + i] = b[i]; }
  for (int i = 0; i < kNS; ++i) { keys[i][0] = outw[2 * i]; keys[i][1] = outw[2 * i + 1]; }
#endif
}

extern "C" void kernel_launch(void* const* d_in, const int* in_sizes, int n_in,
                              void* d_out, int out_size, void* d_ws, size_t ws_size,
                              hipStream_t stream) {
  (void)in_sizes; (void)n_in; (void)out_size; (void)ws_size;
  const float* emb = (const float*)d_in[0];
  const float* W1  = (const float*)d_in[1];
  const float* b1  = (const float*)d_in[2];
  const float* W2  = (const float*)d_in[3];
  const float* b2  = (const float*)d_in[4];
  float* out = (float*)d_out;
  float* ws  = (float*)d_ws;

  float* S       = ws + OFF_SUF;
  float* u       = ws + OFF_U;
  float* snrm    = ws + OFF_SNRM;
  float* lossblk = ws + OFF_LOSSBLK;
  unsigned* bar  = (unsigned*)(ws + OFF_BAR);

  uint32_t keys[kNS][2];
  compute_step_keys(keys);

  // k_suffix also zeroes snrm + barrier counters (ws poisoned before calls);
  // u and lossblk need no zeroing (fully written before read).
  k_suffix<<<8, 256, 0, stream>>>(W1, S, snrm);

  FusedParams p;
  p.S = S; p.emb = emb; p.W1 = W1; p.b1 = b1; p.W2 = W2; p.b2 = b2;
  p.u = u; p.out = out; p.snrm = snrm; p.lossblk = lossblk; p.bar = bar;
  for (int i = 0; i < kNS; ++i) { p.key0[i] = keys[i][0]; p.key1[i] = keys[i][1]; }

  k_fused<<<kNB, 256, 0, stream>>>(p);
}

// Round 3
// 232.925 us; speedup vs baseline: 2.4151x; 2.4151x over previous
//
#include <hip/hip_runtime.h>
#include <stdint.h>

// JAX threefry counter mode. 1 = partitionable (modern JAX default, >=0.4.30).
#define THREEFRY_PARTITIONABLE 1

#define DEV_HOST __host__ __device__

namespace {
constexpr int kNS = 10;
constexpr int kNB = 128;   // persistent grid; 32 samples/block share one W1 row-block

// workspace layout (float offsets)
constexpr int OFF_SUF     = 0;                       // S[j][d][h]: 128*64*32
constexpr int OFF_U       = 262144;                  // u[s][d] handoff
constexpr int OFF_SNRM    = 524288;                  // 16 slots (10 used)
constexpr int OFF_CNT     = 524304;                  // 10 steps x 8 lines x 16 stride
constexpr int OFF_BAR2    = OFF_CNT + 10 * 8 * 16;   // 2 fenced barriers x 8 x 16
constexpr int OFF_LOSSBLK = OFF_BAR2 + 2 * 8 * 16;   // [kNB][2]
constexpr int ZACC_N      = 16 + 10 * 8 * 16 + 2 * 8 * 16;  // 1552, zeroed by k_suffix
}

// ---------------- threefry2x32-20 (matches jax/_src/prng.py) ----------------
DEV_HOST inline void tf2x32(uint32_t k0, uint32_t k1, uint32_t x0, uint32_t x1,
                            uint32_t& o0, uint32_t& o1) {
  const uint32_t k2 = k0 ^ k1 ^ 0x1BD11BDAu;
#define TF_R(r) { x0 += x1; x1 = (x1 << (r)) | (x1 >> (32 - (r))); x1 ^= x0; }
  x0 += k0; x1 += k1;
  TF_R(13) TF_R(15) TF_R(26) TF_R(6)
  x0 += k1; x1 += k2 + 1u;
  TF_R(17) TF_R(29) TF_R(16) TF_R(24)
  x0 += k2; x1 += k0 + 2u;
  TF_R(13) TF_R(15) TF_R(26) TF_R(6)
  x0 += k0; x1 += k1 + 3u;
  TF_R(17) TF_R(29) TF_R(16) TF_R(24)
  x0 += k1; x1 += k2 + 4u;
  TF_R(13) TF_R(15) TF_R(26) TF_R(6)
  x0 += k2; x1 += k0 + 5u;
#undef TF_R
  o0 = x0; o1 = x1;
}

__device__ inline uint32_t rand_bits(uint32_t key0, uint32_t key1, uint32_t idx) {
#if THREEFRY_PARTITIONABLE
  uint32_t y0, y1;
  tf2x32(key0, key1, 0u, idx, y0, y1);
  return y0 ^ y1;
#else
  const uint32_t half = 262144u / 2;
  uint32_t y0, y1;
  if (idx < half) { tf2x32(key0, key1, idx, half + idx, y0, y1); return y0; }
  tf2x32(key0, key1, idx - half, idx, y0, y1);
  return y1;
#endif
}

// ------------- XLA ErfInv (f32, Giles poly) + jax.random.normal -------------
__device__ inline float erfinv_xla(float x) {
  float w = -log1pf(-x * x);
  float p;
  if (w < 5.0f) {
    w = w - 2.5f;
    p = 2.81022636e-08f;
    p = fmaf(p, w, 3.43273939e-07f);
    p = fmaf(p, w, -3.5233877e-06f);
    p = fmaf(p, w, -4.39150654e-06f);
    p = fmaf(p, w, 0.00021858087f);
    p = fmaf(p, w, -0.00125372503f);
    p = fmaf(p, w, -0.00417768164f);
    p = fmaf(p, w, 0.246640727f);
    p = fmaf(p, w, 1.50140941f);
  } else {
    w = sqrtf(w) - 3.0f;
    p = -0.000200214257f;
    p = fmaf(p, w, 0.000100950558f);
    p = fmaf(p, w, 0.00134934322f);
    p = fmaf(p, w, -0.00367342844f);
    p = fmaf(p, w, 0.00573950773f);
    p = fmaf(p, w, -0.0076224613f);
    p = fmaf(p, w, 0.00943887047f);
    p = fmaf(p, w, 1.00167406f);
    p = fmaf(p, w, 2.83297682f);
  }
  return p * x;
}

__device__ inline float bits_to_normal(uint32_t bits) {
  const float lo = -0.99999994039535522f;  // nextafter(-1,0) in f32
  float f = __uint_as_float((bits >> 9) | 0x3f800000u) - 1.0f;
  float u = fmaxf(lo, f * 2.0f + lo);
  return 1.41421356237309515f * erfinv_xla(u);  // sqrt(2) in f32
}

// ---------------------------------------------------------------------------
// FENCED grid barrier (cold path only: u handoff + loss reduce). Proven in
// round 2. The expensive buffer_wbl2/buffer_inv fences are needed here
// because plain stores cross the non-coherent per-XCD L2s.
__device__ inline void gridbar(unsigned* b8, unsigned nblk, bool wait) {
  __syncthreads();
  if (threadIdx.x == 0) {
    __threadfence();  // release: flush dirty L2 so plain stores are visible
    __hip_atomic_fetch_add(b8 + (blockIdx.x & 7) * 16, 1u,
                           __ATOMIC_RELEASE, __HIP_MEMORY_SCOPE_AGENT);
    if (wait) {
      for (;;) {
        unsigned tot = 0;
#pragma unroll
        for (int i = 0; i < 8; ++i)
          tot += __hip_atomic_load(b8 + i * 16, __ATOMIC_RELAXED,
                                   __HIP_MEMORY_SCOPE_AGENT);
        if (tot >= nblk) break;
        __builtin_amdgcn_s_sleep(1);
      }
      __threadfence();  // acquire: invalidate stale caches before consuming
    }
  }
  __syncthreads();
}

// ---------------------------------------------------------------------------
// S[j][d][h] = sum_{t>j} W1[(t*64+d)*32 + h]; also zero snrm/cnt/bar2.
__global__ __launch_bounds__(256) void k_suffix(const float* __restrict__ W1,
                                                float* __restrict__ S,
                                                float* __restrict__ zacc) {
  const int p = blockIdx.x * 256 + threadIdx.x;  // 2048 threads: (d,h)
  if (p < ZACC_N) zacc[p] = 0.0f;
  if (p >= 2048) return;
  const int d = p >> 5, h = p & 31;
  float acc = 0.0f;
  S[(127 * 64 + d) * 32 + h] = 0.0f;
  for (int j = 126; j >= 0; --j) {
    acc += W1[((j + 1) * 64 + d) * 32 + h];
    S[(j * 64 + d) * 32 + h] = acc;
  }
}

// ---------------------------------------------------------------------------
struct FusedParams {
  const float* S;
  const float* emb;
  const float* W1;
  const float* b1;
  const float* W2;
  const float* b2;
  float* u;
  float* out;
  float* snrm;      // [kNS] per-step ||score||^2
  unsigned* cnt;    // [kNS][8*16] step arrival counters (atomic-only path)
  unsigned* bar2;   // [2][8*16] fenced barriers
  float* lossblk;   // [kNB][2]
  uint32_t key0[kNS];
  uint32_t key1[kNS];
};

// Persistent grid, 128 blocks x 256 threads. Block blk owns samples
// s = blk + 128*m (m=0..31) -> all share W1 row-block jw = s&127 = blk, so
// one w1reg[64] column per thread serves its 4 samples. Per step the ONLY
// cross-block payload is the scalar snrm[k], transmitted by device-coherent
// atomics -> the step barrier needs NO cache fences: relaxed fetch_add of
// the partial, s_waitcnt vmcnt(0), relaxed count arrival, relaxed spin,
// relaxed atomic load of the sum.
__global__ __launch_bounds__(256, 1) void k_fused(FusedParams p) {
  __shared__ float u_sh[32][64];
  __shared__ float h_sh[32][32];
  __shared__ float wsum[4];
  __shared__ float wsumB[4];
  __shared__ float snorm_sh;
  const int tid = threadIdx.x;
  const int blk = blockIdx.x;
  const int sl = tid >> 5, c = tid & 31;

  // per-thread samples: s_r = blk + 128*(sl + 8r)
  int sid[4], jj[4];
  bool contrib[4];
#pragma unroll
  for (int r = 0; r < 4; ++r) {
    const int m = sl + 8 * r;
    sid[r] = blk + 128 * m;
    jj[r]  = (blk >> 5) + 4 * m;          // = sid >> 5
    contrib[r] = (blk == jj[r]);          // (s&127) == (s>>5)
  }

  // ---- hoist W1 column + W2 columns into registers (step-invariant) ----
  float w1reg[64];
#pragma unroll
  for (int d = 0; d < 64; ++d) w1reg[d] = p.W1[(blk * 64 + d) * 32 + c];
  const float w1t = p.W1[8192 * 32 + c];
  float w2r0[32], w2r1[32];
#pragma unroll
  for (int hh = 0; hh < 32; ++hh) {
    w2r0[hh] = p.W2[hh * 64 + c];
    w2r1[hh] = p.W2[hh * 64 + c + 32];
  }
  const float b2_0 = p.b2[c], b2_1 = p.b2[c + 32];

  // ---- fused k_base: basev[r] = b1[c] + emb[bb][jj]·S[jj][:,c] ----
  float basev[4];
  {
    const float b1c = p.b1[c];
    const int bb = blk & 31;
#pragma unroll
    for (int r = 0; r < 4; ++r) {
      const float* e  = p.emb + (bb * 128 + jj[r]) * 64;
      const float* Sp = p.S + (jj[r] * 64) * 32 + c;
      float acc = b1c;
#pragma unroll 16
      for (int d = 0; d < 64; ++d) acc = fmaf(e[d], Sp[d * 32], acc);
      basev[r] = acc;
    }
  }

  float u0[4] = {0.f, 0.f, 0.f, 0.f}, u1[4] = {0.f, 0.f, 0.f, 0.f};
  float lacc = 0.0f;
  const unsigned myline = (unsigned)((blk & 7) * 16);

  for (int k = 0; k < kNS; ++k) {
    // stage u into LDS
#pragma unroll
    for (int r = 0; r < 4; ++r) {
      const int m = sl + 8 * r;
      u_sh[m][c]      = u0[r];
      u_sh[m][c + 32] = u1[r];
    }
    __syncthreads();
    // hidden pre-activation + relu (LDS reads are 2-address broadcasts)
    const float tval = (float)k * 0.1f;
#pragma unroll
    for (int r = 0; r < 4; ++r) {
      const int m = sl + 8 * r;
      float pre = fmaf(tval, w1t, basev[r]);
      const float4* up = (const float4*)u_sh[m];
#pragma unroll
      for (int dq = 0; dq < 16; ++dq) {
        const float4 uv = up[dq];
        pre = fmaf(uv.x, w1reg[dq * 4 + 0], pre);
        pre = fmaf(uv.y, w1reg[dq * 4 + 1], pre);
        pre = fmaf(uv.z, w1reg[dq * 4 + 2], pre);
        pre = fmaf(uv.w, w1reg[dq * 4 + 3], pre);
      }
      h_sh[m][c] = fmaxf(pre, 0.0f);
    }
    __syncthreads();
    // score = relu(h) @ W2 + b2 (W2 in regs) + partial ||score||^2
    float sc0[4], sc1[4];
    float sq = 0.0f;
#pragma unroll
    for (int r = 0; r < 4; ++r) {
      const int m = sl + 8 * r;
      float a0 = b2_0, a1 = b2_1;
      const float4* hp = (const float4*)h_sh[m];
#pragma unroll
      for (int hq = 0; hq < 8; ++hq) {
        const float4 hv = hp[hq];
        a0 = fmaf(hv.x, w2r0[hq * 4 + 0], a0); a1 = fmaf(hv.x, w2r1[hq * 4 + 0], a1);
        a0 = fmaf(hv.y, w2r0[hq * 4 + 1], a0); a1 = fmaf(hv.y, w2r1[hq * 4 + 1], a1);
        a0 = fmaf(hv.z, w2r0[hq * 4 + 2], a0); a1 = fmaf(hv.z, w2r1[hq * 4 + 2], a1);
        a0 = fmaf(hv.w, w2r0[hq * 4 + 3], a0); a1 = fmaf(hv.w, w2r1[hq * 4 + 3], a1);
      }
      sc0[r] = a0; sc1[r] = a1;
      sq = fmaf(a0, a0, fmaf(a1, a1, sq));
    }
#pragma unroll
    for (int o = 32; o > 0; o >>= 1) sq += __shfl_down(sq, o);
    if ((tid & 63) == 0) wsum[tid >> 6] = sq;
    __syncthreads();
    // arrive: all-atomic handshake, no fences
    if (tid == 0) {
      const float partial = wsum[0] + wsum[1] + wsum[2] + wsum[3];
      float old = __hip_atomic_fetch_add(p.snrm + k, partial,
                                         __ATOMIC_RELAXED, __HIP_MEMORY_SCOPE_AGENT);
      // ensure the value add reached the coherence point before counting
      asm volatile("s_waitcnt vmcnt(0)" :: "v"(old) : "memory");
      __hip_atomic_fetch_add(p.cnt + (unsigned)k * 128u + myline, 1u,
                             __ATOMIC_RELAXED, __HIP_MEMORY_SCOPE_AGENT);
    }
    // noise for this step (snorm-independent): hides under others' arrivals
    float n0[4], n1[4];
#pragma unroll
    for (int r = 0; r < 4; ++r) {
      const uint32_t e0 = (uint32_t)(sid[r] * 64 + c);
      n0[r] = bits_to_normal(rand_bits(p.key0[k], p.key1[k], e0));
      n1[r] = bits_to_normal(rand_bits(p.key0[k], p.key1[k], e0 + 32u));
    }
    if (tid == 0) {
      unsigned* c8 = p.cnt + (unsigned)k * 128u;
      for (;;) {
        unsigned tot = 0;
#pragma unroll
        for (int i = 0; i < 8; ++i)
          tot += __hip_atomic_load(c8 + i * 16, __ATOMIC_RELAXED,
                                   __HIP_MEMORY_SCOPE_AGENT);
        if (tot >= (unsigned)kNB) break;
        __builtin_amdgcn_s_sleep(1);
      }
      snorm_sh = sqrtf(__hip_atomic_load(p.snrm + k, __ATOMIC_RELAXED,
                                         __HIP_MEMORY_SCOPE_AGENT));
    }
    __syncthreads();
    const float snorm = snorm_sh;
#pragma unroll
    for (int r = 0; r < 4; ++r) {
      u0[r] += sc0[r] * 0.05f + snorm * (n0[r] * 0.31622776601683794f);
      u1[r] += sc1[r] * 0.05f + snorm * (n1[r] * 0.31622776601683794f);
      if (contrib[r]) lacc = fmaf(u0[r], u0[r], fmaf(u1[r], u1[r], lacc));
    }
  }

  // ---- hand off u (plain stores -> fenced barrier, proven path) ----
#pragma unroll
  for (int r = 0; r < 4; ++r) {
    p.u[sid[r] * 64 + c]      = u0[r];
    p.u[sid[r] * 64 + c + 32] = u1[r];
  }
  gridbar(p.bar2, kNB, true);

  // ---- final assembly: xt output + sum|emb-xt| (8 elems/thread) ----
  float lsum = 0.0f;
#pragma unroll
  for (int rr = 0; rr < 8; ++rr) {
    const int g = blk * 256 + tid + rr * 32768;  // g = (b*128+i)*64+d
    const int d = g & 63, bi = g >> 6, i = bi & 127, b = bi >> 7;
    const int m2 = i * 32 + b;
    const int bp = m2 >> 7, t = m2 & 127;
    const int ss = i * 32 + bp;
    float v = 0.0f;
    if (i < t) v = p.emb[(bp * 128 + i) * 64 + d];
    if ((ss & 127) == t) v += p.u[ss * 64 + d];
    p.out[g] = v;
    lsum += fabsf(p.emb[g] - v);
  }
  // block-reduce both loss partials
  float la = lacc * (1.0f / 64.0f);
#pragma unroll
  for (int o = 32; o > 0; o >>= 1) {
    la   += __shfl_down(la, o);
    lsum += __shfl_down(lsum, o);
  }
  if ((tid & 63) == 0) { wsum[tid >> 6] = la; wsumB[tid >> 6] = lsum; }
  __syncthreads();
  if (tid == 0) {
    p.lossblk[2 * blk]     = wsum[0] + wsum[1] + wsum[2] + wsum[3];
    p.lossblk[2 * blk + 1] = wsumB[0] + wsumB[1] + wsumB[2] + wsumB[3];
  }

  // only block 0 waits; others arrive and exit
  gridbar(p.bar2 + 128, kNB, blk == 0);
  if (blk == 0) {
    float a = 0.0f, m = 0.0f;
    for (int q = tid; q < kNB; q += 256) {
      a += p.lossblk[2 * q];
      m += p.lossblk[2 * q + 1];
    }
#pragma unroll
    for (int o = 32; o > 0; o >>= 1) {
      a += __shfl_down(a, o);
      m += __shfl_down(m, o);
    }
    if ((tid & 63) == 0) { wsum[tid >> 6] = a; wsumB[tid >> 6] = m; }
    __syncthreads();
    if (tid == 0) {
      p.out[262144] = wsum[0] + wsum[1] + wsum[2] + wsum[3];                         // step_loss
      p.out[262145] = (wsumB[0] + wsumB[1] + wsumB[2] + wsumB[3]) * (1.0f / 262144.0f);
    }
  }
}

// ---------------------------------------------------------------------------
static void compute_step_keys(uint32_t keys[kNS][2]) {
#if THREEFRY_PARTITIONABLE
  for (int i = 0; i < kNS; ++i) {
    uint32_t y0, y1;
    tf2x32(0u, 42u, 0u, (uint32_t)i, y0, y1);
    keys[i][0] = y0; keys[i][1] = y1;
  }
#else
  uint32_t a[kNS], b[kNS], outw[2 * kNS];
  for (int i = 0; i < kNS; ++i)
    tf2x32(0u, 42u, (uint32_t)i, (uint32_t)(kNS + i), a[i], b[i]);
  for (int i = 0; i < kNS; ++i) { outw[i] = a[i]; outw[kNS + i] = b[i]; }
  for (int i = 0; i < kNS; ++i) { keys[i][0] = outw[2 * i]; keys[i][1] = outw[2 * i + 1]; }
#endif
}

extern "C" void kernel_launch(void* const* d_in, const int* in_sizes, int n_in,
                              void* d_out, int out_size, void* d_ws, size_t ws_size,
                              hipStream_t stream) {
  (void)in_sizes; (void)n_in; (void)out_size; (void)ws_size;
  const float* emb = (const float*)d_in[0];
  const float* W1  = (const float*)d_in[1];
  const float* b1  = (const float*)d_in[2];
  const float* W2  = (const float*)d_in[3];
  const float* b2  = (const float*)d_in[4];
  float* out = (float*)d_out;
  float* ws  = (float*)d_ws;

  float* S       = ws + OFF_SUF;
  float* u       = ws + OFF_U;
  float* snrm    = ws + OFF_SNRM;
  unsigned* cnt  = (unsigned*)(ws + OFF_CNT);
  unsigned* bar2 = (unsigned*)(ws + OFF_BAR2);
  float* lossblk = ws + OFF_LOSSBLK;

  uint32_t keys[kNS][2];
  compute_step_keys(keys);

  // k_suffix also zeroes snrm + cnt + bar2 (contiguous ZACC_N floats).
  k_suffix<<<8, 256, 0, stream>>>(W1, S, snrm);

  FusedParams p;
  p.S = S; p.emb = emb; p.W1 = W1; p.b1 = b1; p.W2 = W2; p.b2 = b2;
  p.u = u; p.out = out; p.snrm = snrm; p.cnt = cnt; p.bar2 = bar2; p.lossblk = lossblk;
  for (int i = 0; i < kNS; ++i) { p.key0[i] = keys[i][0]; p.key1[i] = keys[i][1]; }

  k_fused<<<kNB, 256, 0, stream>>>(p);
}